// Round 5
// baseline (137.569 us; speedup 1.0000x reference)
//
#include <hip/hip_runtime.h>
#include <hip/hip_bf16.h>

// TopologicalMap SOM: x (8192,64) f32, w (64,16384) f32,
// out (8192,16384) f32 = x2[b] + w2[n] - 2 * (x @ w)[b,n]
// Single fused kernel: each block converts its own input tiles (L2-resident),
// computes x2/w2 on the fly, MFMA cross term, nt-store epilogue. No prepass,
// no barriers, no workspace.
#define BATCH 8192
#define IN_D  64
#define OUT_N 16384

typedef __attribute__((ext_vector_type(8)))  short bf16x8;   // 8 bf16 = 4 VGPRs
typedef __attribute__((ext_vector_type(16))) float f32x16;   // 32x32 MFMA acc
typedef __attribute__((ext_vector_type(4)))  float f32x4;

static __device__ inline short bf16cvt(float f) {
    __hip_bfloat16 h = __float2bfloat16(f);
    return *reinterpret_cast<short*>(&h);
}

// Block tile 128x256, 8 waves (2m x 4n), wave tile 64x64 (2x2 frags of 32x32).
__global__ __launch_bounds__(512, 1) void som_fused(
    const float* __restrict__ x, const float* __restrict__ w,
    float* __restrict__ out) {
    // x2 for the block's 128 rows. Each wave writes its OWN wave-row range in
    // full (4 n-waves duplicate identical values) -> same-wave RAW only, no
    // barrier needed.
    __shared__ float x2s[128];

    // bijective XCD swizzle: 4096 blocks = 8 XCDs x 512
    const int bid = blockIdx.x;
    const int swz = (bid & 7) * 512 + (bid >> 3);
    const int bx  = swz & 63;    // n-tile (256 wide)
    const int by  = swz >> 6;    // m-tile (128 tall)

    const int lane = threadIdx.x & 63;
    const int wv   = threadIdx.x >> 6;            // 0..7
    const int wr   = wv >> 2, wc = wv & 3;
    const int m0   = by * 128 + wr * 64;          // wave: 64 rows
    const int n0   = bx * 256 + wc * 64;          // wave: 64 cols
    const int l31  = lane & 31, l5 = lane >> 5;

    // ---- A fragments from x (f32 -> bf16 in reg) + x2 row sums ------------
    // lane covers rows m0+mi*32+l31, k = l5*8 + ks*16 .. +7 (l5 halves are
    // complementary in k -> shfl_xor(32) completes the row sum).
    bf16x8 a[2][4];
    #pragma unroll
    for (int mi = 0; mi < 2; ++mi) {
        const float* xr = x + (size_t)(m0 + mi * 32 + l31) * IN_D + l5 * 8;
        float p = 0.f;
        #pragma unroll
        for (int ks = 0; ks < 4; ++ks) {
            const f32x4 v0 = *reinterpret_cast<const f32x4*>(xr + ks * 16);
            const f32x4 v1 = *reinterpret_cast<const f32x4*>(xr + ks * 16 + 4);
            p += v0[0]*v0[0] + v0[1]*v0[1] + v0[2]*v0[2] + v0[3]*v0[3]
               + v1[0]*v1[0] + v1[1]*v1[1] + v1[2]*v1[2] + v1[3]*v1[3];
            bf16x8 f;
            f[0] = bf16cvt(v0[0]); f[1] = bf16cvt(v0[1]);
            f[2] = bf16cvt(v0[2]); f[3] = bf16cvt(v0[3]);
            f[4] = bf16cvt(v1[0]); f[5] = bf16cvt(v1[1]);
            f[6] = bf16cvt(v1[2]); f[7] = bf16cvt(v1[3]);
            a[mi][ks] = f;
        }
        p += __shfl_xor(p, 32);
        if (l5 == 0) x2s[wr * 64 + mi * 32 + l31] = p;   // full 64-row range per wave
    }

    // ---- B fragments from w (transposed read, f32 -> bf16) + w2 col sums --
    // lane's col = n0+ni*32+l31; k-rows stride OUT_N. Half-wave reads 128B
    // contiguous per k (coalesced); all L2-resident (w = 4MB).
    bf16x8 b[2][4];
    float w2v[2];
    #pragma unroll
    for (int ni = 0; ni < 2; ++ni) {
        const float* wcp = w + n0 + ni * 32 + l31;
        float p = 0.f;
        #pragma unroll
        for (int ks = 0; ks < 4; ++ks) {
            bf16x8 f;
            #pragma unroll
            for (int kk = 0; kk < 8; ++kk) {
                const float v = wcp[(size_t)(l5 * 8 + ks * 16 + kk) * OUT_N];
                p += v * v;
                f[kk] = bf16cvt(v);
            }
            b[ni][ks] = f;
        }
        p += __shfl_xor(p, 32);
        w2v[ni] = p;
    }

    // ---- cross term ---------------------------------------------------------
    f32x16 acc[2][2] = {};
    #pragma unroll
    for (int ks = 0; ks < 4; ++ks)
        #pragma unroll
        for (int mi = 0; mi < 2; ++mi)
            #pragma unroll
            for (int ni = 0; ni < 2; ++ni)
                acc[mi][ni] = __builtin_amdgcn_mfma_f32_32x32x16_bf16(
                    a[mi][ks], b[ni][ks], acc[mi][ni], 0, 0, 0);

    // ---- epilogue: out = x2[row] + w2[col] - 2*cross (R4's nt pattern) ----
    // C layout (m74/m101): col = n0+ni*32+l31, row = (reg&3)+8*(reg>>2)+4*l5.
    #pragma unroll
    for (int ni = 0; ni < 2; ++ni) {
        const float w2c = w2v[ni];
        const size_t colOff = (size_t)(n0 + ni * 32 + l31);
        #pragma unroll
        for (int mi = 0; mi < 2; ++mi) {
            const int rloc = wr * 64 + mi * 32 + 4 * l5;   // LDS-local row base
            const int rbase = by * 128 + rloc;             // global row base
            #pragma unroll
            for (int rg = 0; rg < 4; ++rg) {
                const f32x4 xv = *reinterpret_cast<const f32x4*>(&x2s[rloc + 8 * rg]);
                #pragma unroll
                for (int j = 0; j < 4; ++j) {
                    const int row = rbase + 8 * rg + j;
                    __builtin_nontemporal_store(
                        xv[j] + w2c - 2.0f * acc[mi][ni][4 * rg + j],
                        out + (size_t)row * OUT_N + colOff);
                }
            }
        }
    }
}

extern "C" void kernel_launch(void* const* d_in, const int* in_sizes, int n_in,
                              void* d_out, int out_size, void* d_ws, size_t ws_size,
                              hipStream_t stream) {
    const float* x = (const float*)d_in[0];   // (8192, 64)
    const float* w = (const float*)d_in[1];   // (64, 16384)
    float* out = (float*)d_out;               // (8192, 16384)
    som_fused<<<4096, 512, 0, stream>>>(x, w, out);
}